// Round 10
// baseline (236.841 us; speedup 1.0000x reference)
//
#include <hip/hip_runtime.h>
#include <hip/hip_bf16.h>
#include <hip/hip_fp16.h>
#include <math.h>

#define N_NODES 50000
#define N_EDGES 800000
#define HEADS 4
#define HID 32
#define D1 128
#define D2 64
#define NEG_SLOPE 0.2f
#define LN_EPS 1e-5f

#define GB1N 782                          // ceil(50000/64) gemm row-blocks

// counting-sort geometry (no device-scope atomics anywhere)
#define NCHUNK 128
#define CHE (N_EDGES / NCHUNK)            // 6250 edges per chunk
#define HWORDS (N_NODES / 2)              // 25000 packed u16-pair words (100 KB LDS)
#define HVEC (HWORDS / 4)                 // 6250 uint4
#define CAPS 64                           // fixed col slots per node (P(deg>64) ~ 1e-10)
#define CSCANB ((HWORDS + 255) / 256)     // 98 chunkscan blocks (merged into gemm1 dispatch)

typedef __attribute__((ext_vector_type(8))) short bf16x8;
typedef __attribute__((ext_vector_type(8))) _Float16 f16x8;
typedef __attribute__((ext_vector_type(4))) float f32x4;

__device__ __forceinline__ float lrelu(float x) { return x > 0.f ? x : NEG_SLOPE * x; }

__device__ __forceinline__ short f2bf_s(float x) {
    union { __hip_bfloat16 h; short s; } u;
    u.h = __float2bfloat16(x);
    return u.s;
}
__device__ __forceinline__ float bfs2f(short s) {
    union { unsigned u; float f; } v;
    v.u = ((unsigned)(unsigned short)s) << 16;
    return v.f;
}
__device__ __forceinline__ void split_bf(float x, short& hi, short& lo) {
    hi = f2bf_s(x);
    lo = f2bf_s(x - bfs2f(hi));
}
__device__ __forceinline__ void acc8h(float* acc, uint4 r, float w) {
    union { uint4 u; __half2 h[4]; } q;
    q.u = r;
#pragma unroll
    for (int i = 0; i < 4; ++i) {
        acc[2 * i]     = fmaf(__low2float(q.h[i]), w, acc[2 * i]);
        acc[2 * i + 1] = fmaf(__high2float(q.h[i]), w, acc[2 * i + 1]);
    }
}
__device__ __forceinline__ void acc4h(float* acc, uint2 r, float w) {
    union { uint2 u; __half2 h[2]; } q;
    q.u = r;
    acc[0] = fmaf(__low2float(q.h[0]), w, acc[0]);
    acc[1] = fmaf(__high2float(q.h[0]), w, acc[1]);
    acc[2] = fmaf(__low2float(q.h[1]), w, acc[2]);
    acc[3] = fmaf(__high2float(q.h[1]), w, acc[3]);
}

// ---------------- K1: per-chunk LDS histogram ----------------
__global__ __launch_bounds__(512) void hist_kernel(const int* __restrict__ dst,
                                                   unsigned* __restrict__ hist) {
    __shared__ unsigned cnt[HWORDS];
    int c = blockIdx.x;
    for (int i = threadIdx.x; i < HVEC; i += 512) ((uint4*)cnt)[i] = make_uint4(0, 0, 0, 0);
    __syncthreads();
    int base = c * CHE;
    for (int t = threadIdx.x; t < CHE; t += 512) {
        int d = dst[base + t];
        atomicAdd(&cnt[d >> 1], 1u << ((d & 1) * 16));
    }
    __syncthreads();
    uint4* out = (uint4*)(hist + (size_t)c * HWORDS);
    for (int i = threadIdx.x; i < HVEC; i += 512) out[i] = ((const uint4*)cnt)[i];
}

// ---------------- K2: MFMA gemm1 (+att1 epilogue) with chunkscan blocks merged ----------
// gemm: 64 rows/block, 4 waves; wave w = head w owns cols [32w, 32w+32).
// W fragments self-converted from global f32 (L2-hot) — no wprep stage.
// 3-term bf16 split MFMA: xh*wh + xl*wh + xh*wl (err ~2^-18, fp32-equivalent)
__global__ __launch_bounds__(256, 3) void gemm1_mfma_cscan_kernel(
    const float* __restrict__ X, const float* __restrict__ W,
    __half* __restrict__ Y,
    const float* __restrict__ att_src, const float* __restrict__ att_dst,
    float* __restrict__ a_s, float* __restrict__ a_d,
    unsigned* __restrict__ hist, unsigned* __restrict__ degp) {
    if (blockIdx.x >= GB1N) {
        int wword = (blockIdx.x - GB1N) * 256 + threadIdx.x;
        if (wword >= HWORDS) return;
        unsigned run = 0;
#pragma unroll 8
        for (int c = 0; c < NCHUNK; ++c) {
            unsigned v = hist[(size_t)c * HWORDS + wword];
            hist[(size_t)c * HWORDS + wword] = run;
            run += v;
        }
        degp[wword] = run;
        return;
    }
    int tid = threadIdx.x;
    int w = tid >> 6;   // wave == head
    int l = tid & 63;
    int lr = l & 15;
    int lq = l >> 4;

    // self-convert B fragments: bh/bl[nt][kt][s] = split(W[kt*32+lq*8+s][(2w+nt)*16+lr])
    bf16x8 bh[2][4], bl[2][4];
#pragma unroll
    for (int nt = 0; nt < 2; ++nt)
#pragma unroll
        for (int kt = 0; kt < 4; ++kt) {
            int colIdx = (2 * w + nt) * 16 + lr;
            int rowBase = kt * 32 + lq * 8;
#pragma unroll
            for (int s = 0; s < 8; ++s) {
                short hi, lo;
                split_bf(W[(rowBase + s) * 128 + colIdx], hi, lo);
                bh[nt][kt][s] = hi;
                bl[nt][kt][s] = lo;
            }
        }

    int r0 = blockIdx.x * 64;
    float asv0 = att_src[w * 32 + lr], asv1 = att_src[w * 32 + 16 + lr];
    float adv0 = att_dst[w * 32 + lr], adv1 = att_dst[w * 32 + 16 + lr];

#pragma unroll
    for (int mt = 0; mt < 4; ++mt) {
        int rb = r0 + mt * 16;
        int row = rb + lr;
        if (row >= N_NODES) row = N_NODES - 1;
        const float* xr = X + (size_t)row * 128;
        f32x4 acc0 = {0.f, 0.f, 0.f, 0.f};
        f32x4 acc1 = {0.f, 0.f, 0.f, 0.f};
#pragma unroll
        for (int kt = 0; kt < 4; ++kt) {
            int cb = kt * 32 + lq * 8;
            float4 f0 = *(const float4*)(xr + cb);
            float4 f1 = *(const float4*)(xr + cb + 4);
            float xs[8] = {f0.x, f0.y, f0.z, f0.w, f1.x, f1.y, f1.z, f1.w};
            bf16x8 ah, al;
#pragma unroll
            for (int s = 0; s < 8; ++s) {
                short h_, l_;
                split_bf(xs[s], h_, l_);
                ah[s] = h_;
                al[s] = l_;
            }
            acc0 = __builtin_amdgcn_mfma_f32_16x16x32_bf16(ah, bh[0][kt], acc0, 0, 0, 0);
            acc1 = __builtin_amdgcn_mfma_f32_16x16x32_bf16(ah, bh[1][kt], acc1, 0, 0, 0);
            acc0 = __builtin_amdgcn_mfma_f32_16x16x32_bf16(al, bh[0][kt], acc0, 0, 0, 0);
            acc1 = __builtin_amdgcn_mfma_f32_16x16x32_bf16(al, bh[1][kt], acc1, 0, 0, 0);
            acc0 = __builtin_amdgcn_mfma_f32_16x16x32_bf16(ah, bl[0][kt], acc0, 0, 0, 0);
            acc1 = __builtin_amdgcn_mfma_f32_16x16x32_bf16(ah, bl[1][kt], acc1, 0, 0, 0);
        }
#pragma unroll
        for (int reg = 0; reg < 4; ++reg) {
            int r = rb + lq * 4 + reg;
            float v0 = acc0[reg], v1 = acc1[reg];
            float ps = v0 * asv0 + v1 * asv1;
            float pd = v0 * adv0 + v1 * adv1;
#pragma unroll
            for (int m = 1; m < 16; m <<= 1) {
                ps += __shfl_xor(ps, m, 64);
                pd += __shfl_xor(pd, m, 64);
            }
            if (r < N_NODES) {
                Y[(size_t)r * 128 + w * 32 + lr] = __float2half(v0);
                Y[(size_t)r * 128 + w * 32 + 16 + lr] = __float2half(v1);
                if (lr == 0) {
                    a_s[r * 4 + w] = ps;
                    a_d[r * 4 + w] = pd;
                }
            }
        }
    }
}

// ---------------- K3: scatter into fixed-slot CSR via LDS rank ----------------
__global__ __launch_bounds__(512) void scatter_sorted_kernel(const int* __restrict__ src,
                                                             const int* __restrict__ dst,
                                                             const unsigned* __restrict__ hist,
                                                             int* __restrict__ col) {
    __shared__ unsigned cnt[HWORDS];
    int c = blockIdx.x;
    const uint4* row = (const uint4*)(hist + (size_t)c * HWORDS);
    for (int i = threadIdx.x; i < HVEC; i += 512) ((uint4*)cnt)[i] = row[i];
    __syncthreads();
    int base = c * CHE;
    for (int t = threadIdx.x; t < CHE; t += 512) {
        int d = dst[base + t];
        unsigned old = atomicAdd(&cnt[d >> 1], 1u << ((d & 1) * 16));
        unsigned pos = (old >> ((d & 1) * 16)) & 0xffffu;
        if (pos < CAPS) col[d * CAPS + pos] = src[base + t];
    }
}

// ---------------- K4: agg1 + fused gemm2 (+att2 epilogue) ----------------
// wave per node; lane = eslot(0..3)*16 + ch(0..15); lane covers channels [ch*8, ch*8+8).
// Gather phase barrier-free (colsh/wsh per-wave); fused-gemm2 epilogue uses 2 barriers.
// Epilogue: 4-row x 128 @ 128 x 64 f16 MFMA (wave wv owns cols [wv*16, wv*16+16)).
__global__ __launch_bounds__(256) void agg1_gemm2_kernel(const __half* __restrict__ h,
                                                         const float* __restrict__ a_s,
                                                         const float* __restrict__ a_d,
                                                         const unsigned* __restrict__ degp,
                                                         const int* __restrict__ col,
                                                         const float* __restrict__ b1,
                                                         const float* __restrict__ gamma,
                                                         const float* __restrict__ beta,
                                                         const float* __restrict__ W2,
                                                         const float* __restrict__ att_src2,
                                                         const float* __restrict__ att_dst2,
                                                         __half* __restrict__ h2pre,
                                                         float* __restrict__ a_s2,
                                                         float* __restrict__ a_d2) {
    __shared__ int colsh[4][CAPS];
    __shared__ float wsh[4][CAPS * 4];
    __shared__ _Float16 rowS[4][128];
    __shared__ float psh2[4][4], pdh2[4][4];
    int wv = threadIdx.x >> 6;
    int lane = threadIdx.x & 63;
    int n = blockIdx.x * 4 + wv;
    int nn = (n < N_NODES) ? n : N_NODES - 1;
    int eslot = lane >> 4;   // also MFMA lq
    int ch = lane & 15;      // also MFMA lr
    int head = ch >> 2;

    int deg = (int)((degp[nn >> 1] >> ((nn & 1) * 16)) & 0xffffu);
    if (deg > CAPS) deg = CAPS;
    int beg = nn * CAPS;
    const float4 ad4 = *(const float4*)&a_d[nn * 4];
    // self-loop row load issued early
    uint4 rself = *(const uint4*)(h + (size_t)nn * 128 + ch * 8);

    // pass 1 col load (deg <= 64 -> single round); invalid lanes point at self (safe addr)
    int s_pre = (lane < deg) ? col[beg + lane] : nn;
    // prefetch the first two gather rows via cross-lane shfl of the col values
    int sp0 = __shfl(s_pre, eslot, 64);
    int sp1 = __shfl(s_pre, eslot + 4, 64);
    uint4 rp0 = *(const uint4*)(h + (size_t)sp0 * 128 + ch * 8);
    uint4 rp1 = *(const uint4*)(h + (size_t)sp1 * 128 + ch * 8);

    // weights (exp overlaps the prefetched loads)
    float den0 = 0.f, den1 = 0.f, den2 = 0.f, den3 = 0.f;
    {
        const float4 as4 = *(const float4*)&a_s[s_pre * 4];
        float w0 = __expf(lrelu(as4.x + ad4.x));
        float w1 = __expf(lrelu(as4.y + ad4.y));
        float w2 = __expf(lrelu(as4.z + ad4.z));
        float w3 = __expf(lrelu(as4.w + ad4.w));
        if (lane < deg) {
            colsh[wv][lane] = s_pre;
            *(float4*)&wsh[wv][lane * 4] = make_float4(w0, w1, w2, w3);
            den0 = w0; den1 = w1; den2 = w2; den3 = w3;
        }
    }
    float adh = (head == 0) ? ad4.x : (head == 1) ? ad4.y : (head == 2) ? ad4.z : ad4.w;
    float wself = __expf(lrelu(a_s[nn * 4 + head] + adh));

    // pass 2: consume prefetched rows, then 2-deep pipelined gather
    float acc[8];
#pragma unroll
    for (int i = 0; i < 8; ++i) acc[i] = 0.f;
    if (eslot < deg)     acc8h(acc, rp0, wsh[wv][eslot * 4 + head]);
    if (eslot + 4 < deg) acc8h(acc, rp1, wsh[wv][(eslot + 4) * 4 + head]);
    int t = eslot + 8;
    for (; t + 4 < deg; t += 8) {
        int sa = colsh[wv][t], sb = colsh[wv][t + 4];
        float wa = wsh[wv][t * 4 + head], wb = wsh[wv][(t + 4) * 4 + head];
        uint4 ra = *(const uint4*)(h + (size_t)sa * 128 + ch * 8);
        uint4 rb = *(const uint4*)(h + (size_t)sb * 128 + ch * 8);
        acc8h(acc, ra, wa);
        acc8h(acc, rb, wb);
    }
    if (t < deg) {
        int sa = colsh[wv][t];
        float wa = wsh[wv][t * 4 + head];
        uint4 ra = *(const uint4*)(h + (size_t)sa * 128 + ch * 8);
        acc8h(acc, ra, wa);
    }
    if (eslot == 0) acc8h(acc, rself, wself);

    // combine the 4 edge-slots
#pragma unroll
    for (int i = 0; i < 8; ++i) {
        acc[i] += __shfl_xor(acc[i], 16, 64);
        acc[i] += __shfl_xor(acc[i], 32, 64);
    }
    // denominator reduce (deferred until needed)
#pragma unroll
    for (int m = 1; m < 64; m <<= 1) {
        den0 += __shfl_xor(den0, m, 64);
        den1 += __shfl_xor(den1, m, 64);
        den2 += __shfl_xor(den2, m, 64);
        den3 += __shfl_xor(den3, m, 64);
    }
    float den_h = ((head == 0) ? den0 : (head == 1) ? den1 : (head == 2) ? den2 : den3) + wself;

    float inv = 1.f / den_h;
    const float4 b1a = *(const float4*)&b1[ch * 8];
    const float4 b1b = *(const float4*)&b1[ch * 8 + 4];
    float v[8];
    v[0] = acc[0] * inv + b1a.x; v[1] = acc[1] * inv + b1a.y;
    v[2] = acc[2] * inv + b1a.z; v[3] = acc[3] * inv + b1a.w;
    v[4] = acc[4] * inv + b1b.x; v[5] = acc[5] * inv + b1b.y;
    v[6] = acc[6] * inv + b1b.z; v[7] = acc[7] * inv + b1b.w;

    float s1 = 0.f, s2 = 0.f;
#pragma unroll
    for (int i = 0; i < 8; ++i) { s1 += v[i]; s2 += v[i] * v[i]; }
#pragma unroll
    for (int m = 1; m < 64; m <<= 1) {
        s1 += __shfl_xor(s1, m, 64);
        s2 += __shfl_xor(s2, m, 64);
    }
    // 64 lanes hold 4 copies of the 128-channel sums
    float mean = s1 * (1.f / 512.f);
    float var = s2 * (1.f / 512.f) - mean * mean;
    float rstd = rsqrtf(var + LN_EPS);

    // full-row LN + ReLU -> f16 rowS (eslot==0 copy writes its 8 channels)
    if (eslot == 0) {
        const float4 g1a = *(const float4*)&gamma[ch * 8];
        const float4 g1b = *(const float4*)&gamma[ch * 8 + 4];
        const float4 be1a = *(const float4*)&beta[ch * 8];
        const float4 be1b = *(const float4*)&beta[ch * 8 + 4];
        float gg[8] = {g1a.x, g1a.y, g1a.z, g1a.w, g1b.x, g1b.y, g1b.z, g1b.w};
        float bb[8] = {be1a.x, be1a.y, be1a.z, be1a.w, be1b.x, be1b.y, be1b.z, be1b.w};
#pragma unroll
        for (int i = 0; i < 8; ++i) {
            float o = fmaxf(0.f, (v[i] - mean) * rstd * gg[i] + bb[i]);
            rowS[wv][ch * 8 + i] = (_Float16)o;
        }
    }
    __syncthreads();

    // fused gemm2: B fragments from global f32 W2 (L2-hot), f16 single-term
    f16x8 bfr[4];
#pragma unroll
    for (int kt = 0; kt < 4; ++kt) {
        int rowBase = kt * 32 + eslot * 8;
#pragma unroll
        for (int s = 0; s < 8; ++s)
            bfr[kt][s] = (_Float16)W2[(rowBase + s) * 64 + wv * 16 + ch];
    }
    f32x4 acc2 = {0.f, 0.f, 0.f, 0.f};
#pragma unroll
    for (int kt = 0; kt < 4; ++kt) {
        f16x8 a;
        if (ch < 4) {
            a = *(const f16x8*)&rowS[ch][kt * 32 + eslot * 8];
        } else {
#pragma unroll
            for (int s = 0; s < 8; ++s) a[s] = (_Float16)0.f;
        }
        acc2 = __builtin_amdgcn_mfma_f32_16x16x32_f16(a, bfr[kt], acc2, 0, 0, 0);
    }

    // D rows 0..3 live in eslot==0 lanes (reg = node); att2 epilogue
    float as2v = att_src2[wv * 16 + ch];
    float ad2v = att_dst2[wv * 16 + ch];
#pragma unroll
    for (int reg = 0; reg < 4; ++reg) {
        float hv = acc2[reg];
        float ps = (eslot == 0) ? hv * as2v : 0.f;
        float pd = (eslot == 0) ? hv * ad2v : 0.f;
#pragma unroll
        for (int m = 1; m < 16; m <<= 1) {
            ps += __shfl_xor(ps, m, 64);
            pd += __shfl_xor(pd, m, 64);
        }
        int node = blockIdx.x * 4 + reg;
        if (eslot == 0 && node < N_NODES) {
            h2pre[(size_t)node * 64 + wv * 16 + ch] = __float2half(hv);
            if (ch == 0) { psh2[wv][reg] = ps; pdh2[wv][reg] = pd; }
        }
    }
    __syncthreads();
    if (threadIdx.x < 4) {
        int node = blockIdx.x * 4 + (int)threadIdx.x;
        if (node < N_NODES) {
            a_s2[node] = psh2[0][threadIdx.x] + psh2[1][threadIdx.x] +
                         psh2[2][threadIdx.x] + psh2[3][threadIdx.x];
            a_d2[node] = pdh2[0][threadIdx.x] + pdh2[1][threadIdx.x] +
                         pdh2[2][threadIdx.x] + pdh2[3][threadIdx.x];
        }
    }
}

// ---------------- K5: aggregation layer 2 (4-deep gather pipeline) ----------------
// wave per node; lane = eslot(0..3)*16 + q(0..15); lane covers channels [q*4, q*4+4).
__global__ __launch_bounds__(256) void agg2_kernel(const __half* __restrict__ h,
                                                   const float* __restrict__ a_s,
                                                   const float* __restrict__ a_d,
                                                   const unsigned* __restrict__ degp,
                                                   const int* __restrict__ col,
                                                   const float* __restrict__ b2,
                                                   const float* __restrict__ gamma,
                                                   const float* __restrict__ beta,
                                                   float* __restrict__ out) {
    __shared__ int colsh[4][CAPS];
    __shared__ float wsh[4][CAPS];
    int wv = threadIdx.x >> 6;
    int lane = threadIdx.x & 63;
    int n = blockIdx.x * 4 + wv;
    int nn = (n < N_NODES) ? n : N_NODES - 1;
    int eslot = lane >> 4;
    int q = lane & 15;

    int deg = (int)((degp[nn >> 1] >> ((nn & 1) * 16)) & 0xffffu);
    if (deg > CAPS) deg = CAPS;
    int beg = nn * CAPS;
    float adh = a_d[nn];
    uint2 rself = *(const uint2*)(h + (size_t)nn * 64 + q * 4);

    float den = 0.f;
    if (lane < deg) {
        int s = col[beg + lane];
        float w = __expf(lrelu(a_s[s] + adh));
        colsh[wv][lane] = s;
        wsh[wv][lane] = w;
        den = w;
    }
#pragma unroll
    for (int m = 1; m < 64; m <<= 1) den += __shfl_xor(den, m, 64);
    float wself = __expf(lrelu(a_s[nn] + adh));
    den += wself;

    float acc[4];
#pragma unroll
    for (int i = 0; i < 4; ++i) acc[i] = 0.f;
    int t = eslot;
    for (; t + 12 < deg; t += 16) {
        int s0 = colsh[wv][t], s1 = colsh[wv][t + 4], s2 = colsh[wv][t + 8], s3 = colsh[wv][t + 12];
        float w0 = wsh[wv][t], w1 = wsh[wv][t + 4], w2 = wsh[wv][t + 8], w3 = wsh[wv][t + 12];
        uint2 r0 = *(const uint2*)(h + (size_t)s0 * 64 + q * 4);
        uint2 r1 = *(const uint2*)(h + (size_t)s1 * 64 + q * 4);
        uint2 r2 = *(const uint2*)(h + (size_t)s2 * 64 + q * 4);
        uint2 r3 = *(const uint2*)(h + (size_t)s3 * 64 + q * 4);
        acc4h(acc, r0, w0);
        acc4h(acc, r1, w1);
        acc4h(acc, r2, w2);
        acc4h(acc, r3, w3);
    }
    for (; t + 4 < deg; t += 8) {
        int s0 = colsh[wv][t], s1 = colsh[wv][t + 4];
        float w0 = wsh[wv][t], w1 = wsh[wv][t + 4];
        uint2 r0 = *(const uint2*)(h + (size_t)s0 * 64 + q * 4);
        uint2 r1 = *(const uint2*)(h + (size_t)s1 * 64 + q * 4);
        acc4h(acc, r0, w0);
        acc4h(acc, r1, w1);
    }
    if (t < deg) {
        int s0 = colsh[wv][t];
        float w0 = wsh[wv][t];
        uint2 r0 = *(const uint2*)(h + (size_t)s0 * 64 + q * 4);
        acc4h(acc, r0, w0);
    }
    if (eslot == 0) acc4h(acc, rself, wself);

#pragma unroll
    for (int i = 0; i < 4; ++i) {
        acc[i] += __shfl_xor(acc[i], 16, 64);
        acc[i] += __shfl_xor(acc[i], 32, 64);
    }
    float inv = 1.f / den;
    const float4 b2v = *(const float4*)&b2[q * 4];
    float v[4];
    v[0] = acc[0] * inv + b2v.x;
    v[1] = acc[1] * inv + b2v.y;
    v[2] = acc[2] * inv + b2v.z;
    v[3] = acc[3] * inv + b2v.w;

    float s1 = 0.f, s2 = 0.f;
#pragma unroll
    for (int i = 0; i < 4; ++i) { s1 += v[i]; s2 += v[i] * v[i]; }
#pragma unroll
    for (int m = 1; m < 64; m <<= 1) {
        s1 += __shfl_xor(s1, m, 64);
        s2 += __shfl_xor(s2, m, 64);
    }
    // 64 lanes hold 4 copies of the 64-channel sums
    float mean = s1 * (1.f / 256.f);
    float var = s2 * (1.f / 256.f) - mean * mean;
    float r = rsqrtf(var + LN_EPS);
    if (n < N_NODES && eslot == 0) {
        const float4 g4 = *(const float4*)&gamma[q * 4];
        const float4 be4 = *(const float4*)&beta[q * 4];
        float4 o;
        o.x = (v[0] - mean) * r * g4.x + be4.x;
        o.y = (v[1] - mean) * r * g4.y + be4.y;
        o.z = (v[2] - mean) * r * g4.z + be4.z;
        o.w = (v[3] - mean) * r * g4.w + be4.w;
        *(float4*)&out[(size_t)n * 64 + q * 4] = o;
    }
}

// ---------------- host ----------------
extern "C" void kernel_launch(void* const* d_in, const int* in_sizes, int n_in,
                              void* d_out, int out_size, void* d_ws, size_t ws_size,
                              hipStream_t stream) {
    const float* x        = (const float*)d_in[0];
    const int*   ei       = (const int*)d_in[1];
    const float* W1       = (const float*)d_in[2];
    const float* att_src1 = (const float*)d_in[3];
    const float* att_dst1 = (const float*)d_in[4];
    const float* b1       = (const float*)d_in[5];
    const float* gamma1   = (const float*)d_in[6];
    const float* beta1    = (const float*)d_in[7];
    const float* W2       = (const float*)d_in[8];
    const float* att_src2 = (const float*)d_in[9];
    const float* att_dst2 = (const float*)d_in[10];
    const float* b2       = (const float*)d_in[11];
    const float* gamma2   = (const float*)d_in[12];
    const float* beta2    = (const float*)d_in[13];
    const int* src = ei;
    const int* dst = ei + N_EDGES;
    float* out = (float*)d_out;

    char* ws = (char*)d_ws;
    size_t off = 0;
    auto alloc = [&](size_t bytes) -> void* {
        void* p = ws + off;
        off += bytes;
        off = (off + 255) & ~(size_t)255;
        return p;
    };
    __half* h1pre = (__half*)alloc((size_t)N_NODES * 128 * 2);
    __half* h2pre = (__half*)alloc((size_t)N_NODES * 64 * 2);
    float* a_s1   = (float*)alloc((size_t)N_NODES * 4 * 4);
    float* a_d1   = (float*)alloc((size_t)N_NODES * 4 * 4);
    float* a_s2   = (float*)alloc((size_t)N_NODES * 4);
    float* a_d2   = (float*)alloc((size_t)N_NODES * 4);
    unsigned* hist = (unsigned*)alloc((size_t)NCHUNK * HWORDS * 4);  // 12.8 MB
    unsigned* degp = (unsigned*)alloc((size_t)HWORDS * 4);
    int* col      = (int*)alloc((size_t)N_NODES * CAPS * 4);         // 12.8 MB fixed-slot CSR

    const int NWB = (N_NODES + 3) / 4;

    hist_kernel<<<NCHUNK, 512, 0, stream>>>(dst, hist);
    gemm1_mfma_cscan_kernel<<<GB1N + CSCANB, 256, 0, stream>>>(
        x, W1, h1pre, att_src1, att_dst1, a_s1, a_d1, hist, degp);
    scatter_sorted_kernel<<<NCHUNK, 512, 0, stream>>>(src, dst, hist, col);

    agg1_gemm2_kernel<<<NWB, 256, 0, stream>>>(
        h1pre, a_s1, a_d1, degp, col, b1, gamma1, beta1,
        W2, att_src2, att_dst2, h2pre, a_s2, a_d2);

    agg2_kernel<<<NWB, 256, 0, stream>>>(h2pre, a_s2, a_d2, degp, col, b2, gamma2, beta2, out);
}

// Round 11
// 226.693 us; speedup vs baseline: 1.0448x; 1.0448x over previous
//
#include <hip/hip_runtime.h>
#include <hip/hip_bf16.h>
#include <hip/hip_fp16.h>
#include <math.h>

#define N_NODES 50000
#define N_EDGES 800000
#define HEADS 4
#define HID 32
#define D1 128
#define D2 64
#define NEG_SLOPE 0.2f
#define LN_EPS 1e-5f

#define GB1N 782                          // ceil(50000/64) gemm row-blocks
#define GB2N 782

// counting-sort geometry (no device-scope atomics anywhere)
#define NCHUNK 128
#define CHE (N_EDGES / NCHUNK)            // 6250 edges per chunk
#define HWORDS (N_NODES / 2)              // 25000 packed u16-pair words (100 KB LDS)
#define HVEC (HWORDS / 4)                 // 6250 uint4
#define CAPS 64                           // fixed col slots per node (P(deg>64) ~ 1e-10)
#define CSCANB ((HWORDS + 255) / 256)     // 98 chunkscan blocks (merged into gemm1 dispatch)

typedef __attribute__((ext_vector_type(8))) short bf16x8;
typedef __attribute__((ext_vector_type(8))) _Float16 f16x8;
typedef __attribute__((ext_vector_type(4))) float f32x4;

__device__ __forceinline__ float lrelu(float x) { return x > 0.f ? x : NEG_SLOPE * x; }

__device__ __forceinline__ short f2bf_s(float x) {
    union { __hip_bfloat16 h; short s; } u;
    u.h = __float2bfloat16(x);
    return u.s;
}
__device__ __forceinline__ float bfs2f(short s) {
    union { unsigned u; float f; } v;
    v.u = ((unsigned)(unsigned short)s) << 16;
    return v.f;
}
__device__ __forceinline__ void split_bf(float x, short& hi, short& lo) {
    hi = f2bf_s(x);
    lo = f2bf_s(x - bfs2f(hi));
}
__device__ __forceinline__ void acc8h(float* acc, uint4 r, float w) {
    union { uint4 u; __half2 h[4]; } q;
    q.u = r;
#pragma unroll
    for (int i = 0; i < 4; ++i) {
        acc[2 * i]     = fmaf(__low2float(q.h[i]), w, acc[2 * i]);
        acc[2 * i + 1] = fmaf(__high2float(q.h[i]), w, acc[2 * i + 1]);
    }
}
__device__ __forceinline__ void acc4h(float* acc, uint2 r, float w) {
    union { uint2 u; __half2 h[2]; } q;
    q.u = r;
    acc[0] = fmaf(__low2float(q.h[0]), w, acc[0]);
    acc[1] = fmaf(__high2float(q.h[0]), w, acc[1]);
    acc[2] = fmaf(__low2float(q.h[1]), w, acc[2]);
    acc[3] = fmaf(__high2float(q.h[1]), w, acc[3]);
}

// ---------------- K1: per-chunk LDS histogram ----------------
__global__ __launch_bounds__(512) void hist_kernel(const int* __restrict__ dst,
                                                   unsigned* __restrict__ hist) {
    __shared__ unsigned cnt[HWORDS];
    int c = blockIdx.x;
    for (int i = threadIdx.x; i < HVEC; i += 512) ((uint4*)cnt)[i] = make_uint4(0, 0, 0, 0);
    __syncthreads();
    int base = c * CHE;
    for (int t = threadIdx.x; t < CHE; t += 512) {
        int d = dst[base + t];
        atomicAdd(&cnt[d >> 1], 1u << ((d & 1) * 16));
    }
    __syncthreads();
    uint4* out = (uint4*)(hist + (size_t)c * HWORDS);
    for (int i = threadIdx.x; i < HVEC; i += 512) out[i] = ((const uint4*)cnt)[i];
}

// ---------------- K2: MFMA gemm1 (+att1 epilogue) with chunkscan blocks merged ----------
// gemm: 64 rows/block, 4 waves; wave w = head w owns cols [32w, 32w+32).
// W fragments self-converted from global f32 (L2-hot) — no wprep stage.
// 3-term bf16 split MFMA: xh*wh + xl*wh + xh*wl (err ~2^-18, fp32-equivalent)
__global__ __launch_bounds__(256, 3) void gemm1_mfma_cscan_kernel(
    const float* __restrict__ X, const float* __restrict__ W,
    __half* __restrict__ Y,
    const float* __restrict__ att_src, const float* __restrict__ att_dst,
    float* __restrict__ a_s, float* __restrict__ a_d,
    unsigned* __restrict__ hist, unsigned* __restrict__ degp) {
    if (blockIdx.x >= GB1N) {
        int wword = (blockIdx.x - GB1N) * 256 + threadIdx.x;
        if (wword >= HWORDS) return;
        unsigned run = 0;
#pragma unroll 8
        for (int c = 0; c < NCHUNK; ++c) {
            unsigned v = hist[(size_t)c * HWORDS + wword];
            hist[(size_t)c * HWORDS + wword] = run;
            run += v;
        }
        degp[wword] = run;
        return;
    }
    int tid = threadIdx.x;
    int w = tid >> 6;   // wave == head
    int l = tid & 63;
    int lr = l & 15;
    int lq = l >> 4;

    // self-convert B fragments: bh/bl[nt][kt][s] = split(W[kt*32+lq*8+s][(2w+nt)*16+lr])
    bf16x8 bh[2][4], bl[2][4];
#pragma unroll
    for (int nt = 0; nt < 2; ++nt)
#pragma unroll
        for (int kt = 0; kt < 4; ++kt) {
            int colIdx = (2 * w + nt) * 16 + lr;
            int rowBase = kt * 32 + lq * 8;
#pragma unroll
            for (int s = 0; s < 8; ++s) {
                short hi, lo;
                split_bf(W[(rowBase + s) * 128 + colIdx], hi, lo);
                bh[nt][kt][s] = hi;
                bl[nt][kt][s] = lo;
            }
        }

    int r0 = blockIdx.x * 64;
    float asv0 = att_src[w * 32 + lr], asv1 = att_src[w * 32 + 16 + lr];
    float adv0 = att_dst[w * 32 + lr], adv1 = att_dst[w * 32 + 16 + lr];

#pragma unroll
    for (int mt = 0; mt < 4; ++mt) {
        int rb = r0 + mt * 16;
        int row = rb + lr;
        if (row >= N_NODES) row = N_NODES - 1;
        const float* xr = X + (size_t)row * 128;
        f32x4 acc0 = {0.f, 0.f, 0.f, 0.f};
        f32x4 acc1 = {0.f, 0.f, 0.f, 0.f};
#pragma unroll
        for (int kt = 0; kt < 4; ++kt) {
            int cb = kt * 32 + lq * 8;
            float4 f0 = *(const float4*)(xr + cb);
            float4 f1 = *(const float4*)(xr + cb + 4);
            float xs[8] = {f0.x, f0.y, f0.z, f0.w, f1.x, f1.y, f1.z, f1.w};
            bf16x8 ah, al;
#pragma unroll
            for (int s = 0; s < 8; ++s) {
                short h_, l_;
                split_bf(xs[s], h_, l_);
                ah[s] = h_;
                al[s] = l_;
            }
            acc0 = __builtin_amdgcn_mfma_f32_16x16x32_bf16(ah, bh[0][kt], acc0, 0, 0, 0);
            acc1 = __builtin_amdgcn_mfma_f32_16x16x32_bf16(ah, bh[1][kt], acc1, 0, 0, 0);
            acc0 = __builtin_amdgcn_mfma_f32_16x16x32_bf16(al, bh[0][kt], acc0, 0, 0, 0);
            acc1 = __builtin_amdgcn_mfma_f32_16x16x32_bf16(al, bh[1][kt], acc1, 0, 0, 0);
            acc0 = __builtin_amdgcn_mfma_f32_16x16x32_bf16(ah, bl[0][kt], acc0, 0, 0, 0);
            acc1 = __builtin_amdgcn_mfma_f32_16x16x32_bf16(ah, bl[1][kt], acc1, 0, 0, 0);
        }
#pragma unroll
        for (int reg = 0; reg < 4; ++reg) {
            int r = rb + lq * 4 + reg;
            float v0 = acc0[reg], v1 = acc1[reg];
            float ps = v0 * asv0 + v1 * asv1;
            float pd = v0 * adv0 + v1 * adv1;
#pragma unroll
            for (int m = 1; m < 16; m <<= 1) {
                ps += __shfl_xor(ps, m, 64);
                pd += __shfl_xor(pd, m, 64);
            }
            if (r < N_NODES) {
                Y[(size_t)r * 128 + w * 32 + lr] = __float2half(v0);
                Y[(size_t)r * 128 + w * 32 + 16 + lr] = __float2half(v1);
                if (lr == 0) {
                    a_s[r * 4 + w] = ps;
                    a_d[r * 4 + w] = pd;
                }
            }
        }
    }
}

// ---------------- K3: scatter into fixed-slot CSR via LDS rank ----------------
__global__ __launch_bounds__(512) void scatter_sorted_kernel(const int* __restrict__ src,
                                                             const int* __restrict__ dst,
                                                             const unsigned* __restrict__ hist,
                                                             int* __restrict__ col) {
    __shared__ unsigned cnt[HWORDS];
    int c = blockIdx.x;
    const uint4* row = (const uint4*)(hist + (size_t)c * HWORDS);
    for (int i = threadIdx.x; i < HVEC; i += 512) ((uint4*)cnt)[i] = row[i];
    __syncthreads();
    int base = c * CHE;
    for (int t = threadIdx.x; t < CHE; t += 512) {
        int d = dst[base + t];
        unsigned old = atomicAdd(&cnt[d >> 1], 1u << ((d & 1) * 16));
        unsigned pos = (old >> ((d & 1) * 16)) & 0xffffu;
        if (pos < CAPS) col[d * CAPS + pos] = src[base + t];
    }
}

// ---------------- K5: MFMA gemm2 (+att2 epilogue), single-term f16 ----------------
// h1n is already f16 (its rounding dominates); A-fragments read directly, B = f16(W2).
// Proven numerically by r10's fused variant (absmax unchanged at 0.015625).
__global__ __launch_bounds__(256, 3) void gemm2_mfma_kernel(
    const __half* __restrict__ X, const float* __restrict__ W,
    __half* __restrict__ Y,
    const float* __restrict__ att_src, const float* __restrict__ att_dst,
    float* __restrict__ a_s, float* __restrict__ a_d) {
    __shared__ float psh[4][64];
    __shared__ float pdh[4][64];
    int tid = threadIdx.x;
    int w = tid >> 6;
    int l = tid & 63;
    int lr = l & 15;
    int lq = l >> 4;

    f16x8 bfr[4];
#pragma unroll
    for (int kt = 0; kt < 4; ++kt) {
        int colIdx = w * 16 + lr;
        int rowBase = kt * 32 + lq * 8;
#pragma unroll
        for (int s = 0; s < 8; ++s)
            bfr[kt][s] = (_Float16)W[(rowBase + s) * 64 + colIdx];
    }

    int r0 = blockIdx.x * 64;
    float asv = att_src[w * 16 + lr];
    float adv = att_dst[w * 16 + lr];

    f32x4 acc[4];
#pragma unroll
    for (int mt = 0; mt < 4; ++mt) acc[mt] = (f32x4){0.f, 0.f, 0.f, 0.f};

#pragma unroll
    for (int mt = 0; mt < 4; ++mt) {
        int row = r0 + mt * 16 + lr;
        if (row >= N_NODES) row = N_NODES - 1;
        const __half* xr = X + (size_t)row * 128;
#pragma unroll
        for (int kt = 0; kt < 4; ++kt) {
            int cb = kt * 32 + lq * 8;
            f16x8 a = *(const f16x8*)(xr + cb);
            acc[mt] = __builtin_amdgcn_mfma_f32_16x16x32_f16(a, bfr[kt], acc[mt], 0, 0, 0);
        }
    }

#pragma unroll
    for (int mt = 0; mt < 4; ++mt) {
#pragma unroll
        for (int reg = 0; reg < 4; ++reg) {
            int r = r0 + mt * 16 + lq * 4 + reg;
            float v = acc[mt][reg];
            float ps = v * asv;
            float pd = v * adv;
#pragma unroll
            for (int m = 1; m < 16; m <<= 1) {
                ps += __shfl_xor(ps, m, 64);
                pd += __shfl_xor(pd, m, 64);
            }
            if (r < N_NODES) Y[(size_t)r * 64 + w * 16 + lr] = __float2half(v);
            if (lr == 0) {
                psh[w][mt * 16 + lq * 4 + reg] = ps;
                pdh[w][mt * 16 + lq * 4 + reg] = pd;
            }
        }
    }
    __syncthreads();
    if (tid < 64) {
        int r = r0 + tid;
        if (r < N_NODES) {
            a_s[r] = psh[0][tid] + psh[1][tid] + psh[2][tid] + psh[3][tid];
            a_d[r] = pdh[0][tid] + pdh[1][tid] + pdh[2][tid] + pdh[3][tid];
        }
    }
}

// ---------------- K4: aggregation layer 1 (r8 shape: shfl-prefetch + late den) --------
// wave per node; lane = eslot(0..3)*16 + ch(0..15); lane covers channels [ch*8, ch*8+8).
// No __syncthreads: colsh/wsh strictly per-wave.
__global__ __launch_bounds__(256) void agg1_kernel(const __half* __restrict__ h,
                                                   const float* __restrict__ a_s,
                                                   const float* __restrict__ a_d,
                                                   const unsigned* __restrict__ degp,
                                                   const int* __restrict__ col,
                                                   const float* __restrict__ b1,
                                                   const float* __restrict__ gamma,
                                                   const float* __restrict__ beta,
                                                   __half* __restrict__ out) {
    __shared__ int colsh[4][CAPS];
    __shared__ float wsh[4][CAPS * 4];
    int wv = threadIdx.x >> 6;
    int lane = threadIdx.x & 63;
    int n = blockIdx.x * 4 + wv;
    int nn = (n < N_NODES) ? n : N_NODES - 1;
    int eslot = lane >> 4;
    int ch = lane & 15;
    int head = ch >> 2;

    int deg = (int)((degp[nn >> 1] >> ((nn & 1) * 16)) & 0xffffu);
    if (deg > CAPS) deg = CAPS;
    int beg = nn * CAPS;
    const float4 ad4 = *(const float4*)&a_d[nn * 4];
    // self-loop row load issued early
    uint4 rself = *(const uint4*)(h + (size_t)nn * 128 + ch * 8);

    // pass 1 col load (deg <= 64 -> single round); invalid lanes point at self (safe addr)
    int s_pre = (lane < deg) ? col[beg + lane] : nn;
    // prefetch the first two gather rows via cross-lane shfl of the col values
    int sp0 = __shfl(s_pre, eslot, 64);
    int sp1 = __shfl(s_pre, eslot + 4, 64);
    uint4 rp0 = *(const uint4*)(h + (size_t)sp0 * 128 + ch * 8);
    uint4 rp1 = *(const uint4*)(h + (size_t)sp1 * 128 + ch * 8);

    // weights (exp overlaps the prefetched loads)
    float den0 = 0.f, den1 = 0.f, den2 = 0.f, den3 = 0.f;
    {
        const float4 as4 = *(const float4*)&a_s[s_pre * 4];
        float w0 = __expf(lrelu(as4.x + ad4.x));
        float w1 = __expf(lrelu(as4.y + ad4.y));
        float w2 = __expf(lrelu(as4.z + ad4.z));
        float w3 = __expf(lrelu(as4.w + ad4.w));
        if (lane < deg) {
            colsh[wv][lane] = s_pre;
            *(float4*)&wsh[wv][lane * 4] = make_float4(w0, w1, w2, w3);
            den0 = w0; den1 = w1; den2 = w2; den3 = w3;
        }
    }
    float adh = (head == 0) ? ad4.x : (head == 1) ? ad4.y : (head == 2) ? ad4.z : ad4.w;
    float wself = __expf(lrelu(a_s[nn * 4 + head] + adh));

    // pass 2: consume prefetched rows, then 2-deep pipelined gather
    float acc[8];
#pragma unroll
    for (int i = 0; i < 8; ++i) acc[i] = 0.f;
    if (eslot < deg)     acc8h(acc, rp0, wsh[wv][eslot * 4 + head]);
    if (eslot + 4 < deg) acc8h(acc, rp1, wsh[wv][(eslot + 4) * 4 + head]);
    int t = eslot + 8;
    for (; t + 4 < deg; t += 8) {
        int sa = colsh[wv][t], sb = colsh[wv][t + 4];
        float wa = wsh[wv][t * 4 + head], wb = wsh[wv][(t + 4) * 4 + head];
        uint4 ra = *(const uint4*)(h + (size_t)sa * 128 + ch * 8);
        uint4 rb = *(const uint4*)(h + (size_t)sb * 128 + ch * 8);
        acc8h(acc, ra, wa);
        acc8h(acc, rb, wb);
    }
    if (t < deg) {
        int sa = colsh[wv][t];
        float wa = wsh[wv][t * 4 + head];
        uint4 ra = *(const uint4*)(h + (size_t)sa * 128 + ch * 8);
        acc8h(acc, ra, wa);
    }
    if (eslot == 0) acc8h(acc, rself, wself);

    // combine the 4 edge-slots
#pragma unroll
    for (int i = 0; i < 8; ++i) {
        acc[i] += __shfl_xor(acc[i], 16, 64);
        acc[i] += __shfl_xor(acc[i], 32, 64);
    }
    // denominator reduce (deferred until needed)
#pragma unroll
    for (int m = 1; m < 64; m <<= 1) {
        den0 += __shfl_xor(den0, m, 64);
        den1 += __shfl_xor(den1, m, 64);
        den2 += __shfl_xor(den2, m, 64);
        den3 += __shfl_xor(den3, m, 64);
    }
    float den_h = ((head == 0) ? den0 : (head == 1) ? den1 : (head == 2) ? den2 : den3) + wself;

    float inv = 1.f / den_h;
    const float4 b1a = *(const float4*)&b1[ch * 8];
    const float4 b1b = *(const float4*)&b1[ch * 8 + 4];
    float v[8];
    v[0] = acc[0] * inv + b1a.x; v[1] = acc[1] * inv + b1a.y;
    v[2] = acc[2] * inv + b1a.z; v[3] = acc[3] * inv + b1a.w;
    v[4] = acc[4] * inv + b1b.x; v[5] = acc[5] * inv + b1b.y;
    v[6] = acc[6] * inv + b1b.z; v[7] = acc[7] * inv + b1b.w;

    float s1 = 0.f, s2 = 0.f;
#pragma unroll
    for (int i = 0; i < 8; ++i) { s1 += v[i]; s2 += v[i] * v[i]; }
#pragma unroll
    for (int m = 1; m < 64; m <<= 1) {
        s1 += __shfl_xor(s1, m, 64);
        s2 += __shfl_xor(s2, m, 64);
    }
    // 64 lanes hold 4 copies of the 128-channel sums
    float mean = s1 * (1.f / 512.f);
    float var = s2 * (1.f / 512.f) - mean * mean;
    float r = rsqrtf(var + LN_EPS);
    int c0 = ch * 8 + eslot * 2;
    const float2 g2 = *(const float2*)&gamma[c0];
    const float2 be2 = *(const float2*)&beta[c0];
    float ox = fmaxf(0.f, (v[eslot * 2] - mean) * r * g2.x + be2.x);
    float oy = fmaxf(0.f, (v[eslot * 2 + 1] - mean) * r * g2.y + be2.y);
    if (n < N_NODES) {
        __half2 p;
        p.x = __float2half(ox);
        p.y = __float2half(oy);
        *(__half2*)&out[(size_t)n * 128 + c0] = p;
    }
}

// ---------------- K6: aggregation layer 2 (4-deep gather pipeline) ----------------
// wave per node; lane = eslot(0..3)*16 + q(0..15); lane covers channels [q*4, q*4+4).
__global__ __launch_bounds__(256) void agg2_kernel(const __half* __restrict__ h,
                                                   const float* __restrict__ a_s,
                                                   const float* __restrict__ a_d,
                                                   const unsigned* __restrict__ degp,
                                                   const int* __restrict__ col,
                                                   const float* __restrict__ b2,
                                                   const float* __restrict__ gamma,
                                                   const float* __restrict__ beta,
                                                   float* __restrict__ out) {
    __shared__ int colsh[4][CAPS];
    __shared__ float wsh[4][CAPS];
    int wv = threadIdx.x >> 6;
    int lane = threadIdx.x & 63;
    int n = blockIdx.x * 4 + wv;
    int nn = (n < N_NODES) ? n : N_NODES - 1;
    int eslot = lane >> 4;
    int q = lane & 15;

    int deg = (int)((degp[nn >> 1] >> ((nn & 1) * 16)) & 0xffffu);
    if (deg > CAPS) deg = CAPS;
    int beg = nn * CAPS;
    float adh = a_d[nn];
    uint2 rself = *(const uint2*)(h + (size_t)nn * 64 + q * 4);

    float den = 0.f;
    if (lane < deg) {
        int s = col[beg + lane];
        float w = __expf(lrelu(a_s[s] + adh));
        colsh[wv][lane] = s;
        wsh[wv][lane] = w;
        den = w;
    }
#pragma unroll
    for (int m = 1; m < 64; m <<= 1) den += __shfl_xor(den, m, 64);
    float wself = __expf(lrelu(a_s[nn] + adh));
    den += wself;

    float acc[4];
#pragma unroll
    for (int i = 0; i < 4; ++i) acc[i] = 0.f;
    int t = eslot;
    for (; t + 12 < deg; t += 16) {
        int s0 = colsh[wv][t], s1 = colsh[wv][t + 4], s2 = colsh[wv][t + 8], s3 = colsh[wv][t + 12];
        float w0 = wsh[wv][t], w1 = wsh[wv][t + 4], w2 = wsh[wv][t + 8], w3 = wsh[wv][t + 12];
        uint2 r0 = *(const uint2*)(h + (size_t)s0 * 64 + q * 4);
        uint2 r1 = *(const uint2*)(h + (size_t)s1 * 64 + q * 4);
        uint2 r2 = *(const uint2*)(h + (size_t)s2 * 64 + q * 4);
        uint2 r3 = *(const uint2*)(h + (size_t)s3 * 64 + q * 4);
        acc4h(acc, r0, w0);
        acc4h(acc, r1, w1);
        acc4h(acc, r2, w2);
        acc4h(acc, r3, w3);
    }
    for (; t + 4 < deg; t += 8) {
        int s0 = colsh[wv][t], s1 = colsh[wv][t + 4];
        float w0 = wsh[wv][t], w1 = wsh[wv][t + 4];
        uint2 r0 = *(const uint2*)(h + (size_t)s0 * 64 + q * 4);
        uint2 r1 = *(const uint2*)(h + (size_t)s1 * 64 + q * 4);
        acc4h(acc, r0, w0);
        acc4h(acc, r1, w1);
    }
    if (t < deg) {
        int s0 = colsh[wv][t];
        float w0 = wsh[wv][t];
        uint2 r0 = *(const uint2*)(h + (size_t)s0 * 64 + q * 4);
        acc4h(acc, r0, w0);
    }
    if (eslot == 0) acc4h(acc, rself, wself);

#pragma unroll
    for (int i = 0; i < 4; ++i) {
        acc[i] += __shfl_xor(acc[i], 16, 64);
        acc[i] += __shfl_xor(acc[i], 32, 64);
    }
    float inv = 1.f / den;
    const float4 b2v = *(const float4*)&b2[q * 4];
    float v[4];
    v[0] = acc[0] * inv + b2v.x;
    v[1] = acc[1] * inv + b2v.y;
    v[2] = acc[2] * inv + b2v.z;
    v[3] = acc[3] * inv + b2v.w;

    float s1 = 0.f, s2 = 0.f;
#pragma unroll
    for (int i = 0; i < 4; ++i) { s1 += v[i]; s2 += v[i] * v[i]; }
#pragma unroll
    for (int m = 1; m < 64; m <<= 1) {
        s1 += __shfl_xor(s1, m, 64);
        s2 += __shfl_xor(s2, m, 64);
    }
    // 64 lanes hold 4 copies of the 64-channel sums
    float mean = s1 * (1.f / 256.f);
    float var = s2 * (1.f / 256.f) - mean * mean;
    float r = rsqrtf(var + LN_EPS);
    if (n < N_NODES && eslot == 0) {
        const float4 g4 = *(const float4*)&gamma[q * 4];
        const float4 be4 = *(const float4*)&beta[q * 4];
        float4 o;
        o.x = (v[0] - mean) * r * g4.x + be4.x;
        o.y = (v[1] - mean) * r * g4.y + be4.y;
        o.z = (v[2] - mean) * r * g4.z + be4.z;
        o.w = (v[3] - mean) * r * g4.w + be4.w;
        *(float4*)&out[(size_t)n * 64 + q * 4] = o;
    }
}

// ---------------- host ----------------
extern "C" void kernel_launch(void* const* d_in, const int* in_sizes, int n_in,
                              void* d_out, int out_size, void* d_ws, size_t ws_size,
                              hipStream_t stream) {
    const float* x        = (const float*)d_in[0];
    const int*   ei       = (const int*)d_in[1];
    const float* W1       = (const float*)d_in[2];
    const float* att_src1 = (const float*)d_in[3];
    const float* att_dst1 = (const float*)d_in[4];
    const float* b1       = (const float*)d_in[5];
    const float* gamma1   = (const float*)d_in[6];
    const float* beta1    = (const float*)d_in[7];
    const float* W2       = (const float*)d_in[8];
    const float* att_src2 = (const float*)d_in[9];
    const float* att_dst2 = (const float*)d_in[10];
    const float* b2       = (const float*)d_in[11];
    const float* gamma2   = (const float*)d_in[12];
    const float* beta2    = (const float*)d_in[13];
    const int* src = ei;
    const int* dst = ei + N_EDGES;
    float* out = (float*)d_out;

    char* ws = (char*)d_ws;
    size_t off = 0;
    auto alloc = [&](size_t bytes) -> void* {
        void* p = ws + off;
        off += bytes;
        off = (off + 255) & ~(size_t)255;
        return p;
    };
    __half* h1pre = (__half*)alloc((size_t)N_NODES * 128 * 2);
    __half* h2pre = (__half*)alloc((size_t)N_NODES * 64 * 2);
    float* a_s1   = (float*)alloc((size_t)N_NODES * 4 * 4);
    float* a_d1   = (float*)alloc((size_t)N_NODES * 4 * 4);
    __half* h1n   = (__half*)alloc((size_t)N_NODES * 128 * 2);
    float* a_s2   = (float*)alloc((size_t)N_NODES * 4);
    float* a_d2   = (float*)alloc((size_t)N_NODES * 4);
    unsigned* hist = (unsigned*)alloc((size_t)NCHUNK * HWORDS * 4);  // 12.8 MB
    unsigned* degp = (unsigned*)alloc((size_t)HWORDS * 4);
    int* col      = (int*)alloc((size_t)N_NODES * CAPS * 4);         // 12.8 MB fixed-slot CSR

    const int NWB = (N_NODES + 3) / 4;

    hist_kernel<<<NCHUNK, 512, 0, stream>>>(dst, hist);
    gemm1_mfma_cscan_kernel<<<GB1N + CSCANB, 256, 0, stream>>>(
        x, W1, h1pre, att_src1, att_dst1, a_s1, a_d1, hist, degp);
    scatter_sorted_kernel<<<NCHUNK, 512, 0, stream>>>(src, dst, hist, col);

    agg1_kernel<<<NWB, 256, 0, stream>>>(h1pre, a_s1, a_d1, degp, col, b1, gamma1, beta1, h1n);

    gemm2_mfma_kernel<<<GB2N, 256, 0, stream>>>(
        h1n, W2, h2pre, att_src2, att_dst2, a_s2, a_d2);
    agg2_kernel<<<NWB, 256, 0, stream>>>(h2pre, a_s2, a_d2, degp, col, b2, gamma2, beta2, out);
}

// Round 12
// 219.795 us; speedup vs baseline: 1.0776x; 1.0314x over previous
//
#include <hip/hip_runtime.h>
#include <hip/hip_bf16.h>
#include <hip/hip_fp16.h>
#include <math.h>

#define N_NODES 50000
#define N_EDGES 800000
#define HEADS 4
#define HID 32
#define D1 128
#define D2 64
#define NEG_SLOPE 0.2f
#define LN_EPS 1e-5f

#define GB1N 782                          // ceil(50000/64) gemm row-blocks
#define GB2N 782

// counting-sort geometry (no device-scope atomics anywhere)
#define NCHUNK 128
#define CHE (N_EDGES / NCHUNK)            // 6250 edges per chunk
#define HWORDS (N_NODES / 2)              // 25000 packed u16-pair words (100 KB LDS)
#define HVEC (HWORDS / 4)                 // 6250 uint4
#define CAPS 64                           // fixed col slots per node (P(deg>64) ~ 1e-10)
#define CSCANB ((HWORDS + 255) / 256)     // 98 chunkscan blocks (merged into gemm1 dispatch)

typedef __attribute__((ext_vector_type(8))) short bf16x8;
typedef __attribute__((ext_vector_type(8))) _Float16 f16x8;
typedef __attribute__((ext_vector_type(4))) float f32x4;

__device__ __forceinline__ float lrelu(float x) { return x > 0.f ? x : NEG_SLOPE * x; }

__device__ __forceinline__ short f2bf_s(float x) {
    union { __hip_bfloat16 h; short s; } u;
    u.h = __float2bfloat16(x);
    return u.s;
}
__device__ __forceinline__ float bfs2f(short s) {
    union { unsigned u; float f; } v;
    v.u = ((unsigned)(unsigned short)s) << 16;
    return v.f;
}
__device__ __forceinline__ void split_bf(float x, short& hi, short& lo) {
    hi = f2bf_s(x);
    lo = f2bf_s(x - bfs2f(hi));
}
__device__ __forceinline__ void acc8h(float* acc, uint4 r, float w) {
    union { uint4 u; __half2 h[4]; } q;
    q.u = r;
#pragma unroll
    for (int i = 0; i < 4; ++i) {
        acc[2 * i]     = fmaf(__low2float(q.h[i]), w, acc[2 * i]);
        acc[2 * i + 1] = fmaf(__high2float(q.h[i]), w, acc[2 * i + 1]);
    }
}
__device__ __forceinline__ void acc4h(float* acc, uint2 r, float w) {
    union { uint2 u; __half2 h[2]; } q;
    q.u = r;
    acc[0] = fmaf(__low2float(q.h[0]), w, acc[0]);
    acc[1] = fmaf(__high2float(q.h[0]), w, acc[1]);
    acc[2] = fmaf(__low2float(q.h[1]), w, acc[2]);
    acc[3] = fmaf(__high2float(q.h[1]), w, acc[3]);
}

// ---------------- K1: per-chunk LDS histogram ----------------
__global__ __launch_bounds__(512) void hist_kernel(const int* __restrict__ dst,
                                                   unsigned* __restrict__ hist) {
    __shared__ unsigned cnt[HWORDS];
    int c = blockIdx.x;
    for (int i = threadIdx.x; i < HVEC; i += 512) ((uint4*)cnt)[i] = make_uint4(0, 0, 0, 0);
    __syncthreads();
    int base = c * CHE;
    for (int t = threadIdx.x; t < CHE; t += 512) {
        int d = dst[base + t];
        atomicAdd(&cnt[d >> 1], 1u << ((d & 1) * 16));
    }
    __syncthreads();
    uint4* out = (uint4*)(hist + (size_t)c * HWORDS);
    for (int i = threadIdx.x; i < HVEC; i += 512) out[i] = ((const uint4*)cnt)[i];
}

// ---------------- K2: MFMA gemm1 (+att1 epilogue) with chunkscan blocks merged ----------
// gemm: 64 rows/block, 4 waves; wave w = head w owns cols [32w, 32w+32).
// W fragments self-converted from global f32 (L2-hot) — no wprep stage.
// 3-term bf16 split MFMA: xh*wh + xl*wh + xh*wl (err ~2^-18, fp32-equivalent)
__global__ __launch_bounds__(256, 3) void gemm1_mfma_cscan_kernel(
    const float* __restrict__ X, const float* __restrict__ W,
    __half* __restrict__ Y,
    const float* __restrict__ att_src, const float* __restrict__ att_dst,
    float* __restrict__ a_s, float* __restrict__ a_d,
    unsigned* __restrict__ hist, unsigned* __restrict__ degp) {
    if (blockIdx.x >= GB1N) {
        int wword = (blockIdx.x - GB1N) * 256 + threadIdx.x;
        if (wword >= HWORDS) return;
        unsigned run = 0;
#pragma unroll 8
        for (int c = 0; c < NCHUNK; ++c) {
            unsigned v = hist[(size_t)c * HWORDS + wword];
            hist[(size_t)c * HWORDS + wword] = run;
            run += v;
        }
        degp[wword] = run;
        return;
    }
    int tid = threadIdx.x;
    int w = tid >> 6;   // wave == head
    int l = tid & 63;
    int lr = l & 15;
    int lq = l >> 4;

    // self-convert B fragments: bh/bl[nt][kt][s] = split(W[kt*32+lq*8+s][(2w+nt)*16+lr])
    bf16x8 bh[2][4], bl[2][4];
#pragma unroll
    for (int nt = 0; nt < 2; ++nt)
#pragma unroll
        for (int kt = 0; kt < 4; ++kt) {
            int colIdx = (2 * w + nt) * 16 + lr;
            int rowBase = kt * 32 + lq * 8;
#pragma unroll
            for (int s = 0; s < 8; ++s) {
                short hi, lo;
                split_bf(W[(rowBase + s) * 128 + colIdx], hi, lo);
                bh[nt][kt][s] = hi;
                bl[nt][kt][s] = lo;
            }
        }

    int r0 = blockIdx.x * 64;
    float asv0 = att_src[w * 32 + lr], asv1 = att_src[w * 32 + 16 + lr];
    float adv0 = att_dst[w * 32 + lr], adv1 = att_dst[w * 32 + 16 + lr];

#pragma unroll
    for (int mt = 0; mt < 4; ++mt) {
        int rb = r0 + mt * 16;
        int row = rb + lr;
        if (row >= N_NODES) row = N_NODES - 1;
        const float* xr = X + (size_t)row * 128;
        f32x4 acc0 = {0.f, 0.f, 0.f, 0.f};
        f32x4 acc1 = {0.f, 0.f, 0.f, 0.f};
#pragma unroll
        for (int kt = 0; kt < 4; ++kt) {
            int cb = kt * 32 + lq * 8;
            float4 f0 = *(const float4*)(xr + cb);
            float4 f1 = *(const float4*)(xr + cb + 4);
            float xs[8] = {f0.x, f0.y, f0.z, f0.w, f1.x, f1.y, f1.z, f1.w};
            bf16x8 ah, al;
#pragma unroll
            for (int s = 0; s < 8; ++s) {
                short h_, l_;
                split_bf(xs[s], h_, l_);
                ah[s] = h_;
                al[s] = l_;
            }
            acc0 = __builtin_amdgcn_mfma_f32_16x16x32_bf16(ah, bh[0][kt], acc0, 0, 0, 0);
            acc1 = __builtin_amdgcn_mfma_f32_16x16x32_bf16(ah, bh[1][kt], acc1, 0, 0, 0);
            acc0 = __builtin_amdgcn_mfma_f32_16x16x32_bf16(al, bh[0][kt], acc0, 0, 0, 0);
            acc1 = __builtin_amdgcn_mfma_f32_16x16x32_bf16(al, bh[1][kt], acc1, 0, 0, 0);
            acc0 = __builtin_amdgcn_mfma_f32_16x16x32_bf16(ah, bl[0][kt], acc0, 0, 0, 0);
            acc1 = __builtin_amdgcn_mfma_f32_16x16x32_bf16(ah, bl[1][kt], acc1, 0, 0, 0);
        }
#pragma unroll
        for (int reg = 0; reg < 4; ++reg) {
            int r = rb + lq * 4 + reg;
            float v0 = acc0[reg], v1 = acc1[reg];
            float ps = v0 * asv0 + v1 * asv1;
            float pd = v0 * adv0 + v1 * adv1;
#pragma unroll
            for (int m = 1; m < 16; m <<= 1) {
                ps += __shfl_xor(ps, m, 64);
                pd += __shfl_xor(pd, m, 64);
            }
            if (r < N_NODES) {
                Y[(size_t)r * 128 + w * 32 + lr] = __float2half(v0);
                Y[(size_t)r * 128 + w * 32 + 16 + lr] = __float2half(v1);
                if (lr == 0) {
                    a_s[r * 4 + w] = ps;
                    a_d[r * 4 + w] = pd;
                }
            }
        }
    }
}

// ---------------- K3: scatter into fixed-slot CSR via LDS rank ----------------
__global__ __launch_bounds__(512) void scatter_sorted_kernel(const int* __restrict__ src,
                                                             const int* __restrict__ dst,
                                                             const unsigned* __restrict__ hist,
                                                             int* __restrict__ col) {
    __shared__ unsigned cnt[HWORDS];
    int c = blockIdx.x;
    const uint4* row = (const uint4*)(hist + (size_t)c * HWORDS);
    for (int i = threadIdx.x; i < HVEC; i += 512) ((uint4*)cnt)[i] = row[i];
    __syncthreads();
    int base = c * CHE;
    for (int t = threadIdx.x; t < CHE; t += 512) {
        int d = dst[base + t];
        unsigned old = atomicAdd(&cnt[d >> 1], 1u << ((d & 1) * 16));
        unsigned pos = (old >> ((d & 1) * 16)) & 0xffffu;
        if (pos < CAPS) col[d * CAPS + pos] = src[base + t];
    }
}

// ---------------- K5: MFMA gemm2 (+att2 epilogue), single-term f16 ----------------
// h1n is already f16 (its rounding dominates); A-fragments read directly, B = f16(W2).
// Proven numerically by r10's fused variant (absmax unchanged at 0.015625).
__global__ __launch_bounds__(256, 3) void gemm2_mfma_kernel(
    const __half* __restrict__ X, const float* __restrict__ W,
    __half* __restrict__ Y,
    const float* __restrict__ att_src, const float* __restrict__ att_dst,
    float* __restrict__ a_s, float* __restrict__ a_d) {
    __shared__ float psh[4][64];
    __shared__ float pdh[4][64];
    int tid = threadIdx.x;
    int w = tid >> 6;
    int l = tid & 63;
    int lr = l & 15;
    int lq = l >> 4;

    f16x8 bfr[4];
#pragma unroll
    for (int kt = 0; kt < 4; ++kt) {
        int colIdx = w * 16 + lr;
        int rowBase = kt * 32 + lq * 8;
#pragma unroll
        for (int s = 0; s < 8; ++s)
            bfr[kt][s] = (_Float16)W[(rowBase + s) * 64 + colIdx];
    }

    int r0 = blockIdx.x * 64;
    float asv = att_src[w * 16 + lr];
    float adv = att_dst[w * 16 + lr];

    f32x4 acc[4];
#pragma unroll
    for (int mt = 0; mt < 4; ++mt) acc[mt] = (f32x4){0.f, 0.f, 0.f, 0.f};

#pragma unroll
    for (int mt = 0; mt < 4; ++mt) {
        int row = r0 + mt * 16 + lr;
        if (row >= N_NODES) row = N_NODES - 1;
        const __half* xr = X + (size_t)row * 128;
#pragma unroll
        for (int kt = 0; kt < 4; ++kt) {
            int cb = kt * 32 + lq * 8;
            f16x8 a = *(const f16x8*)(xr + cb);
            acc[mt] = __builtin_amdgcn_mfma_f32_16x16x32_f16(a, bfr[kt], acc[mt], 0, 0, 0);
        }
    }

#pragma unroll
    for (int mt = 0; mt < 4; ++mt) {
#pragma unroll
        for (int reg = 0; reg < 4; ++reg) {
            int r = r0 + mt * 16 + lq * 4 + reg;
            float v = acc[mt][reg];
            float ps = v * asv;
            float pd = v * adv;
#pragma unroll
            for (int m = 1; m < 16; m <<= 1) {
                ps += __shfl_xor(ps, m, 64);
                pd += __shfl_xor(pd, m, 64);
            }
            if (r < N_NODES) Y[(size_t)r * 64 + w * 16 + lr] = __float2half(v);
            if (lr == 0) {
                psh[w][mt * 16 + lq * 4 + reg] = ps;
                pdh[w][mt * 16 + lq * 4 + reg] = pd;
            }
        }
    }
    __syncthreads();
    if (tid < 64) {
        int r = r0 + tid;
        if (r < N_NODES) {
            a_s[r] = psh[0][tid] + psh[1][tid] + psh[2][tid] + psh[3][tid];
            a_d[r] = pdh[0][tid] + pdh[1][tid] + pdh[2][tid] + pdh[3][tid];
        }
    }
}

// ---------------- K4: aggregation layer 1 (r8 shape: shfl-prefetch + late den) --------
// wave per node; lane = eslot(0..3)*16 + ch(0..15); lane covers channels [ch*8, ch*8+8).
// No __syncthreads: colsh/wsh strictly per-wave.
__global__ __launch_bounds__(256) void agg1_kernel(const __half* __restrict__ h,
                                                   const float* __restrict__ a_s,
                                                   const float* __restrict__ a_d,
                                                   const unsigned* __restrict__ degp,
                                                   const int* __restrict__ col,
                                                   const float* __restrict__ b1,
                                                   const float* __restrict__ gamma,
                                                   const float* __restrict__ beta,
                                                   __half* __restrict__ out) {
    __shared__ int colsh[4][CAPS];
    __shared__ float wsh[4][CAPS * 4];
    int wv = threadIdx.x >> 6;
    int lane = threadIdx.x & 63;
    int n = blockIdx.x * 4 + wv;
    int nn = (n < N_NODES) ? n : N_NODES - 1;
    int eslot = lane >> 4;
    int ch = lane & 15;
    int head = ch >> 2;

    int deg = (int)((degp[nn >> 1] >> ((nn & 1) * 16)) & 0xffffu);
    if (deg > CAPS) deg = CAPS;
    int beg = nn * CAPS;
    const float4 ad4 = *(const float4*)&a_d[nn * 4];
    // self-loop row load issued early
    uint4 rself = *(const uint4*)(h + (size_t)nn * 128 + ch * 8);

    // pass 1 col load (deg <= 64 -> single round); invalid lanes point at self (safe addr)
    int s_pre = (lane < deg) ? col[beg + lane] : nn;
    // prefetch the first two gather rows via cross-lane shfl of the col values
    int sp0 = __shfl(s_pre, eslot, 64);
    int sp1 = __shfl(s_pre, eslot + 4, 64);
    uint4 rp0 = *(const uint4*)(h + (size_t)sp0 * 128 + ch * 8);
    uint4 rp1 = *(const uint4*)(h + (size_t)sp1 * 128 + ch * 8);

    // weights (exp overlaps the prefetched loads)
    float den0 = 0.f, den1 = 0.f, den2 = 0.f, den3 = 0.f;
    {
        const float4 as4 = *(const float4*)&a_s[s_pre * 4];
        float w0 = __expf(lrelu(as4.x + ad4.x));
        float w1 = __expf(lrelu(as4.y + ad4.y));
        float w2 = __expf(lrelu(as4.z + ad4.z));
        float w3 = __expf(lrelu(as4.w + ad4.w));
        if (lane < deg) {
            colsh[wv][lane] = s_pre;
            *(float4*)&wsh[wv][lane * 4] = make_float4(w0, w1, w2, w3);
            den0 = w0; den1 = w1; den2 = w2; den3 = w3;
        }
    }
    float adh = (head == 0) ? ad4.x : (head == 1) ? ad4.y : (head == 2) ? ad4.z : ad4.w;
    float wself = __expf(lrelu(a_s[nn * 4 + head] + adh));

    // pass 2: consume prefetched rows, then 2-deep pipelined gather
    float acc[8];
#pragma unroll
    for (int i = 0; i < 8; ++i) acc[i] = 0.f;
    if (eslot < deg)     acc8h(acc, rp0, wsh[wv][eslot * 4 + head]);
    if (eslot + 4 < deg) acc8h(acc, rp1, wsh[wv][(eslot + 4) * 4 + head]);
    int t = eslot + 8;
    for (; t + 4 < deg; t += 8) {
        int sa = colsh[wv][t], sb = colsh[wv][t + 4];
        float wa = wsh[wv][t * 4 + head], wb = wsh[wv][(t + 4) * 4 + head];
        uint4 ra = *(const uint4*)(h + (size_t)sa * 128 + ch * 8);
        uint4 rb = *(const uint4*)(h + (size_t)sb * 128 + ch * 8);
        acc8h(acc, ra, wa);
        acc8h(acc, rb, wb);
    }
    if (t < deg) {
        int sa = colsh[wv][t];
        float wa = wsh[wv][t * 4 + head];
        uint4 ra = *(const uint4*)(h + (size_t)sa * 128 + ch * 8);
        acc8h(acc, ra, wa);
    }
    if (eslot == 0) acc8h(acc, rself, wself);

    // combine the 4 edge-slots
#pragma unroll
    for (int i = 0; i < 8; ++i) {
        acc[i] += __shfl_xor(acc[i], 16, 64);
        acc[i] += __shfl_xor(acc[i], 32, 64);
    }
    // denominator reduce (deferred until needed)
#pragma unroll
    for (int m = 1; m < 64; m <<= 1) {
        den0 += __shfl_xor(den0, m, 64);
        den1 += __shfl_xor(den1, m, 64);
        den2 += __shfl_xor(den2, m, 64);
        den3 += __shfl_xor(den3, m, 64);
    }
    float den_h = ((head == 0) ? den0 : (head == 1) ? den1 : (head == 2) ? den2 : den3) + wself;

    float inv = 1.f / den_h;
    const float4 b1a = *(const float4*)&b1[ch * 8];
    const float4 b1b = *(const float4*)&b1[ch * 8 + 4];
    float v[8];
    v[0] = acc[0] * inv + b1a.x; v[1] = acc[1] * inv + b1a.y;
    v[2] = acc[2] * inv + b1a.z; v[3] = acc[3] * inv + b1a.w;
    v[4] = acc[4] * inv + b1b.x; v[5] = acc[5] * inv + b1b.y;
    v[6] = acc[6] * inv + b1b.z; v[7] = acc[7] * inv + b1b.w;

    float s1 = 0.f, s2 = 0.f;
#pragma unroll
    for (int i = 0; i < 8; ++i) { s1 += v[i]; s2 += v[i] * v[i]; }
#pragma unroll
    for (int m = 1; m < 64; m <<= 1) {
        s1 += __shfl_xor(s1, m, 64);
        s2 += __shfl_xor(s2, m, 64);
    }
    // 64 lanes hold 4 copies of the 128-channel sums
    float mean = s1 * (1.f / 512.f);
    float var = s2 * (1.f / 512.f) - mean * mean;
    float r = rsqrtf(var + LN_EPS);
    int c0 = ch * 8 + eslot * 2;
    const float2 g2 = *(const float2*)&gamma[c0];
    const float2 be2 = *(const float2*)&beta[c0];
    float ox = fmaxf(0.f, (v[eslot * 2] - mean) * r * g2.x + be2.x);
    float oy = fmaxf(0.f, (v[eslot * 2 + 1] - mean) * r * g2.y + be2.y);
    if (n < N_NODES) {
        __half2 p;
        p.x = __float2half(ox);
        p.y = __float2half(oy);
        *(__half2*)&out[(size_t)n * 128 + c0] = p;
    }
}

// ---------------- K6: aggregation layer 2 (r8 shape: shfl-prefetch + late den) --------
// wave per node; lane = eslot(0..3)*16 + q(0..15); lane covers channels [q*4, q*4+4).
// No __syncthreads: colsh/wsh strictly per-wave.
__global__ __launch_bounds__(256) void agg2_kernel(const __half* __restrict__ h,
                                                   const float* __restrict__ a_s,
                                                   const float* __restrict__ a_d,
                                                   const unsigned* __restrict__ degp,
                                                   const int* __restrict__ col,
                                                   const float* __restrict__ b2,
                                                   const float* __restrict__ gamma,
                                                   const float* __restrict__ beta,
                                                   float* __restrict__ out) {
    __shared__ int colsh[4][CAPS];
    __shared__ float wsh[4][CAPS];
    int wv = threadIdx.x >> 6;
    int lane = threadIdx.x & 63;
    int n = blockIdx.x * 4 + wv;
    int nn = (n < N_NODES) ? n : N_NODES - 1;
    int eslot = lane >> 4;
    int q = lane & 15;

    int deg = (int)((degp[nn >> 1] >> ((nn & 1) * 16)) & 0xffffu);
    if (deg > CAPS) deg = CAPS;
    int beg = nn * CAPS;
    float adh = a_d[nn];
    // self-loop row load issued early
    uint2 rself = *(const uint2*)(h + (size_t)nn * 64 + q * 4);

    // pass 1 col load (deg <= 64 -> single round); invalid lanes point at self (safe addr)
    int s_pre = (lane < deg) ? col[beg + lane] : nn;
    // prefetch the first two gather rows via cross-lane shfl of the col values
    int sp0 = __shfl(s_pre, eslot, 64);
    int sp1 = __shfl(s_pre, eslot + 4, 64);
    uint2 rp0 = *(const uint2*)(h + (size_t)sp0 * 64 + q * 4);
    uint2 rp1 = *(const uint2*)(h + (size_t)sp1 * 64 + q * 4);

    // weights (exp overlaps the prefetched loads)
    float den = 0.f;
    {
        float w = __expf(lrelu(a_s[s_pre] + adh));
        if (lane < deg) {
            colsh[wv][lane] = s_pre;
            wsh[wv][lane] = w;
            den = w;
        }
    }
    float wself = __expf(lrelu(a_s[nn] + adh));

    // pass 2: consume prefetched rows, then 2-deep pipelined gather
    float acc[4];
#pragma unroll
    for (int i = 0; i < 4; ++i) acc[i] = 0.f;
    if (eslot < deg)     acc4h(acc, rp0, wsh[wv][eslot]);
    if (eslot + 4 < deg) acc4h(acc, rp1, wsh[wv][eslot + 4]);
    int t = eslot + 8;
    for (; t + 4 < deg; t += 8) {
        int sa = colsh[wv][t], sb = colsh[wv][t + 4];
        float wa = wsh[wv][t], wb = wsh[wv][t + 4];
        uint2 ra = *(const uint2*)(h + (size_t)sa * 64 + q * 4);
        uint2 rb = *(const uint2*)(h + (size_t)sb * 64 + q * 4);
        acc4h(acc, ra, wa);
        acc4h(acc, rb, wb);
    }
    if (t < deg) {
        int sa = colsh[wv][t];
        float wa = wsh[wv][t];
        uint2 ra = *(const uint2*)(h + (size_t)sa * 64 + q * 4);
        acc4h(acc, ra, wa);
    }
    if (eslot == 0) acc4h(acc, rself, wself);

    // combine the 4 edge-slots
#pragma unroll
    for (int i = 0; i < 4; ++i) {
        acc[i] += __shfl_xor(acc[i], 16, 64);
        acc[i] += __shfl_xor(acc[i], 32, 64);
    }
    // denominator reduce (deferred until needed)
#pragma unroll
    for (int m = 1; m < 64; m <<= 1) den += __shfl_xor(den, m, 64);
    den += wself;

    float inv = 1.f / den;
    const float4 b2v = *(const float4*)&b2[q * 4];
    float v[4];
    v[0] = acc[0] * inv + b2v.x;
    v[1] = acc[1] * inv + b2v.y;
    v[2] = acc[2] * inv + b2v.z;
    v[3] = acc[3] * inv + b2v.w;

    float s1 = 0.f, s2 = 0.f;
#pragma unroll
    for (int i = 0; i < 4; ++i) { s1 += v[i]; s2 += v[i] * v[i]; }
#pragma unroll
    for (int m = 1; m < 64; m <<= 1) {
        s1 += __shfl_xor(s1, m, 64);
        s2 += __shfl_xor(s2, m, 64);
    }
    // 64 lanes hold 4 copies of the 64-channel sums
    float mean = s1 * (1.f / 256.f);
    float var = s2 * (1.f / 256.f) - mean * mean;
    float r = rsqrtf(var + LN_EPS);
    if (n < N_NODES && eslot == 0) {
        const float4 g4 = *(const float4*)&gamma[q * 4];
        const float4 be4 = *(const float4*)&beta[q * 4];
        float4 o;
        o.x = (v[0] - mean) * r * g4.x + be4.x;
        o.y = (v[1] - mean) * r * g4.y + be4.y;
        o.z = (v[2] - mean) * r * g4.z + be4.z;
        o.w = (v[3] - mean) * r * g4.w + be4.w;
        *(float4*)&out[(size_t)n * 64 + q * 4] = o;
    }
}

// ---------------- host ----------------
extern "C" void kernel_launch(void* const* d_in, const int* in_sizes, int n_in,
                              void* d_out, int out_size, void* d_ws, size_t ws_size,
                              hipStream_t stream) {
    const float* x        = (const float*)d_in[0];
    const int*   ei       = (const int*)d_in[1];
    const float* W1       = (const float*)d_in[2];
    const float* att_src1 = (const float*)d_in[3];
    const float* att_dst1 = (const float*)d_in[4];
    const float* b1       = (const float*)d_in[5];
    const float* gamma1   = (const float*)d_in[6];
    const float* beta1    = (const float*)d_in[7];
    const float* W2       = (const float*)d_in[8];
    const float* att_src2 = (const float*)d_in[9];
    const float* att_dst2 = (const float*)d_in[10];
    const float* b2       = (const float*)d_in[11];
    const float* gamma2   = (const float*)d_in[12];
    const float* beta2    = (const float*)d_in[13];
    const int* src = ei;
    const int* dst = ei + N_EDGES;
    float* out = (float*)d_out;

    char* ws = (char*)d_ws;
    size_t off = 0;
    auto alloc = [&](size_t bytes) -> void* {
        void* p = ws + off;
        off += bytes;
        off = (off + 255) & ~(size_t)255;
        return p;
    };
    __half* h1pre = (__half*)alloc((size_t)N_NODES * 128 * 2);
    __half* h2pre = (__half*)alloc((size_t)N_NODES * 64 * 2);
    float* a_s1   = (float*)alloc((size_t)N_NODES * 4 * 4);
    float* a_d1   = (float*)alloc((size_t)N_NODES * 4 * 4);
    __half* h1n   = (__half*)alloc((size_t)N_NODES * 128 * 2);
    float* a_s2   = (float*)alloc((size_t)N_NODES * 4);
    float* a_d2   = (float*)alloc((size_t)N_NODES * 4);
    unsigned* hist = (unsigned*)alloc((size_t)NCHUNK * HWORDS * 4);  // 12.8 MB
    unsigned* degp = (unsigned*)alloc((size_t)HWORDS * 4);
    int* col      = (int*)alloc((size_t)N_NODES * CAPS * 4);         // 12.8 MB fixed-slot CSR

    const int NWB = (N_NODES + 3) / 4;

    hist_kernel<<<NCHUNK, 512, 0, stream>>>(dst, hist);
    gemm1_mfma_cscan_kernel<<<GB1N + CSCANB, 256, 0, stream>>>(
        x, W1, h1pre, att_src1, att_dst1, a_s1, a_d1, hist, degp);
    scatter_sorted_kernel<<<NCHUNK, 512, 0, stream>>>(src, dst, hist, col);

    agg1_kernel<<<NWB, 256, 0, stream>>>(h1pre, a_s1, a_d1, degp, col, b1, gamma1, beta1, h1n);

    gemm2_mfma_kernel<<<GB2N, 256, 0, stream>>>(
        h1n, W2, h2pre, att_src2, att_dst2, a_s2, a_d2);
    agg2_kernel<<<NWB, 256, 0, stream>>>(h2pre, a_s2, a_d2, degp, col, b2, gamma2, beta2, out);
}